// Round 3
// baseline (307.098 us; speedup 1.0000x reference)
//
#include <hip/hip_runtime.h>
#include <hip/hip_bf16.h>

// SlicingLinearBlock: out[16384,4096] = x[16384,256] @ B[256,4096] (fp32),
// B[k,o] = W[k/8, o, k%8].
//
// R2 structure: NO LDS, NO BARRIERS in the GEMM. Prepasses pack x and W into
// bf16 *MFMA fragment order*: FragArr[tile16][kc][lane] of 16 B, where
// lane = (k_group<<4) | (row&15), k = kc*32 + k_group*8 + j (j=0..7).
// The GEMM loads each wave's A/B fragments directly from global memory with
// perfectly coalesced global_load_dwordx4 (base + lane*16); B2 (2 MB) lives
// in per-XCD L2, A2 (8 MB) in L3. Register double-buffer over the 8-step
// K-loop lets the compiler emit partial vmcnt waits (no barrier forces a
// vmcnt(0) drain) — every wave pipelines independently.
//
// Workspace: [0, 8MB) A2 = x fragments; [8MB, 10MB) B2 = W fragments.

typedef __attribute__((ext_vector_type(8)))  __bf16          bf16x8;
typedef __attribute__((ext_vector_type(8)))  unsigned short  ushort8;
typedef __attribute__((ext_vector_type(4)))  float           floatx4;

__device__ __forceinline__ unsigned short f2bf(float f) {
    union { float f; unsigned u; } v; v.f = f;
    unsigned r = v.u + 0x7fffu + ((v.u >> 16) & 1u);   // RNE
    return (unsigned short)(r >> 16);
}

// x[16384,256] fp32 -> A2 fragment order. Thread u: mt=u>>9, kc=(u>>6)&7,
// lane=u&63; reads x[mt*16+(lane&15)][kc*32+(lane>>4)*8 .. +8] (32 B, no
// over-fetch: wave covers 16 aligned 128 B segments), writes 16 B coalesced.
__global__ void pack_x_kernel(const float* __restrict__ x,
                              unsigned short* __restrict__ A2) {
    const int u    = blockIdx.x * 256 + threadIdx.x;   // 524288 threads
    const int lane = u & 63;
    const int kc   = (u >> 6) & 7;
    const int mt   = u >> 9;
    const int r    = mt * 16 + (lane & 15);
    const int k    = kc * 32 + (lane >> 4) * 8;
    const float4* p = (const float4*)(x + (size_t)r * 256 + k);
    float4 a = p[0], b = p[1];
    ushort8 v;
    v[0] = f2bf(a.x); v[1] = f2bf(a.y); v[2] = f2bf(a.z); v[3] = f2bf(a.w);
    v[4] = f2bf(b.x); v[5] = f2bf(b.y); v[6] = f2bf(b.z); v[7] = f2bf(b.w);
    *(ushort8*)(A2 + (size_t)u * 8) = v;
}

// W[32,4096,8] fp32 -> B2 fragment order. Bt[o][k]=W[k/8][o][k%8]; the 8
// contiguous c-values of W[s][o][.] ARE one fragment's 8 k-elements
// (k = s*8+c -> kc = s>>2, kg = s&3). Thread u: nt=u>>9, kc=(u>>6)&7,
// lane=u&63, o = nt*16+(lane&15), s = kc*4+(lane>>4). Reads 32 B contiguous
// per thread (consecutive threads contiguous), writes 16 B coalesced.
__global__ void pack_w_kernel(const float* __restrict__ W,
                              unsigned short* __restrict__ B2) {
    const int u    = blockIdx.x * 256 + threadIdx.x;   // 131072 threads
    const int lane = u & 63;
    const int kc   = (u >> 6) & 7;
    const int nt   = u >> 9;
    const int o    = nt * 16 + (lane & 15);
    const int s    = kc * 4 + (lane >> 4);
    const float4* p = (const float4*)(W + ((size_t)s * 4096 + o) * 8);
    float4 a = p[0], b = p[1];
    ushort8 v;
    v[0] = f2bf(a.x); v[1] = f2bf(a.y); v[2] = f2bf(a.z); v[3] = f2bf(a.w);
    v[4] = f2bf(b.x); v[5] = f2bf(b.y); v[6] = f2bf(b.z); v[7] = f2bf(b.w);
    *(ushort8*)(B2 + (size_t)u * 8) = v;
}

// C[16384,4096] fp32. Block = 4 waves (2x2), block tile 128x128, wave tile
// 64x64 as 4x4 of 16x16x32 MFMA. Fragments straight from global; register
// double-buffer over kc; zero LDS, zero __syncthreads.
__global__ __launch_bounds__(256) void gemm_kernel(
    const unsigned short* __restrict__ A2,
    const unsigned short* __restrict__ B2,
    float* __restrict__ C) {
    const int tid  = threadIdx.x;
    const int wave = tid >> 6;
    const int lane = tid & 63;
    const int bm   = blockIdx.y;     // 0..127
    const int bn   = blockIdx.x;     // 0..31
    const int wrow = wave >> 1, wcol = wave & 1;

    // fragment (i, kc) of this wave: base + i*4096 + kc*512 (ushorts)
    const unsigned short* Ab = A2 + ((size_t)(bm * 8 + wrow * 4) * 4096) + lane * 8;
    const unsigned short* Bb = B2 + ((size_t)(bn * 8 + wcol * 4) * 4096) + lane * 8;

    floatx4 acc[4][4] = {};
    bf16x8 af[2][4], bf[2][4];

#pragma unroll
    for (int i = 0; i < 4; ++i) {
        af[0][i] = *(const bf16x8*)(const void*)(Ab + i * 4096);
        bf[0][i] = *(const bf16x8*)(const void*)(Bb + i * 4096);
    }

#pragma unroll
    for (int kc = 0; kc < 8; ++kc) {
        const int cur = kc & 1, nxt = cur ^ 1;
        if (kc < 7) {
            const int ko = (kc + 1) * 512;
#pragma unroll
            for (int i = 0; i < 4; ++i) {
                af[nxt][i] = *(const bf16x8*)(const void*)(Ab + i * 4096 + ko);
                bf[nxt][i] = *(const bf16x8*)(const void*)(Bb + i * 4096 + ko);
            }
        }
#pragma unroll
        for (int i = 0; i < 4; ++i)
#pragma unroll
            for (int j = 0; j < 4; ++j)
                acc[i][j] = __builtin_amdgcn_mfma_f32_16x16x32_bf16(
                    af[cur][i], bf[cur][j], acc[i][j], 0, 0, 0);
    }

    // epilogue: C/D layout col = lane&15, row = (lane>>4)*4 + reg (verified).
    // Non-temporal: C is write-once; keep L2 for A/B fragment re-reads.
    const int fr = lane & 15;
    const int fq = lane >> 4;
    const int row0 = bm * 128 + wrow * 64 + fq * 4;
    const int col0 = bn * 128 + wcol * 64 + fr;
#pragma unroll
    for (int i = 0; i < 4; ++i) {
#pragma unroll
        for (int j = 0; j < 4; ++j) {
            float* Cp = C + (size_t)(row0 + i * 16) * 4096 + col0 + j * 16;
#pragma unroll
            for (int r = 0; r < 4; ++r)
                __builtin_nontemporal_store(acc[i][j][r], Cp + (size_t)r * 4096);
        }
    }
}

extern "C" void kernel_launch(void* const* d_in, const int* in_sizes, int n_in,
                              void* d_out, int out_size, void* d_ws, size_t ws_size,
                              hipStream_t stream) {
    const float* x = (const float*)d_in[0];   // [16384, 256]
    const float* W = (const float*)d_in[1];   // [32, 4096, 8]
    float* out = (float*)d_out;               // [16384, 4096]

    unsigned short* A2 = (unsigned short*)d_ws;            // 8 MB
    unsigned short* B2 = A2 + (size_t)16384 * 256;         // +2 MB

    pack_x_kernel<<<2048, 256, 0, stream>>>(x, A2);
    pack_w_kernel<<<512, 256, 0, stream>>>(W, B2);

    dim3 grid(32, 128);   // bn = 4096/128, bm = 16384/128
    gemm_kernel<<<grid, 256, 0, stream>>>(A2, B2, out);
}